// Round 5
// baseline (185.475 us; speedup 1.0000x reference)
//
#include <hip/hip_runtime.h>
#include <math.h>

// FutureEncoder: B=4, S=2048, D=1024, FUTURE_K=32, fp32 in/out.
// R5: back to pure-VALU, zero barriers, max wave count.
// One wave per token (8192 waves). Two-pass: (1) 32 scores via 16-dim
// partial dots + butterfly (4 rows interleaved), softmax in registers,
// (2) re-stream rows (L1/L2 hot) with plain weighted accumulate.
// XCD-contiguous swizzle keeps each XCD's working set ~4 MiB = its L2.

constexpr int S = 2048;
constexpr int D = 1024;
constexpr int KF = 32;

__global__ __launch_bounds__(256, 4)
void future_encoder_kernel(const float* __restrict__ h,
                           float* __restrict__ out,
                           int ntok) {
    // XCD swizzle: contiguous 256-block chunk per XCD (1024 tokens = 4 MiB)
    int bid = blockIdx.x, nblk = gridDim.x, lb = bid;
    if ((nblk & 7) == 0) { int per = nblk >> 3; lb = (bid & 7) * per + (bid >> 3); }

    const int t    = lb * 4 + (threadIdx.x >> 6);   // token id (wave id)
    const int lane = threadIdx.x & 63;
    if (t >= ntok) return;

    const int s    = t & (S - 1);
    const int kmax = min(KF, (S - 1) - s);          // # valid future rows
    const int tmax = ntok - 1;
    const int doff = lane * 4;                      // 4 interleaved float4 chunks

    const float* qp = h + (size_t)t * D + doff;
    const float4 q0 = *(const float4*)(qp + 0);
    const float4 q1 = *(const float4*)(qp + 256);
    const float4 q2 = *(const float4*)(qp + 512);
    const float4 q3 = *(const float4*)(qp + 768);

    float sc[KF];

    // ---------------- pass 1: scores (4 rows per group, butterflies interleaved)
    #pragma unroll 2
    for (int g = 0; g < KF / 4; ++g) {
        float p[4];
        #pragma unroll
        for (int r = 0; r < 4; ++r) {
            const int j   = g * 4 + r;
            const int row = min(t + 1 + j, tmax);   // clamp; masked at softmax
            const float* fp = h + (size_t)row * D + doff;
            const float4 f0 = *(const float4*)(fp + 0);
            const float4 f1 = *(const float4*)(fp + 256);
            const float4 f2 = *(const float4*)(fp + 512);
            const float4 f3 = *(const float4*)(fp + 768);
            // 4 independent FMA chains -> short dependency depth
            float d0 = f0.x*q0.x + f0.y*q0.y + f0.z*q0.z + f0.w*q0.w;
            float d1 = f1.x*q1.x + f1.y*q1.y + f1.z*q1.z + f1.w*q1.w;
            float d2 = f2.x*q2.x + f2.y*q2.y + f2.z*q2.z + f2.w*q2.w;
            float d3 = f3.x*q3.x + f3.y*q3.y + f3.z*q3.z + f3.w*q3.w;
            p[r] = (d0 + d1) + (d2 + d3);
        }
        #pragma unroll
        for (int i = 1; i < 64; i <<= 1) {          // 4 interleaved butterflies
            p[0] += __shfl_xor(p[0], i, 64);
            p[1] += __shfl_xor(p[1], i, 64);
            p[2] += __shfl_xor(p[2], i, 64);
            p[3] += __shfl_xor(p[3], i, 64);
        }
        sc[g * 4 + 0] = p[0];
        sc[g * 4 + 1] = p[1];
        sc[g * 4 + 2] = p[2];
        sc[g * 4 + 3] = p[3];
    }

    // ---------------- softmax over 32 register scores (wave-uniform values)
    float m = -1e30f;
    #pragma unroll
    for (int j = 0; j < KF; ++j) {
        sc[j] = (j < kmax) ? sc[j] : -1e30f;        // mask invalid (wave-uniform)
        m = fmaxf(m, sc[j]);
    }
    float sum = 0.f;
    #pragma unroll
    for (int j = 0; j < KF; ++j) {
        float e = __expf(sc[j] - m);                // invalid: exp(-huge)=0
        sc[j] = e;
        sum += e;
    }
    const float inv = (kmax > 0) ? (1.0f / sum) : 0.f;  // kmax==0 -> all-zero out
    #pragma unroll
    for (int j = 0; j < KF; ++j) sc[j] *= inv;

    // ---------------- pass 2: weighted accumulate (rows hot in L1/L2)
    float4 a0 = {0,0,0,0}, a1 = {0,0,0,0}, a2 = {0,0,0,0}, a3 = {0,0,0,0};
    #pragma unroll 4
    for (int j = 0; j < KF; ++j) {
        const int row = min(t + 1 + j, tmax);
        const float* fp = h + (size_t)row * D + doff;
        const float w = sc[j];                      // 0 for invalid rows
        const float4 f0 = *(const float4*)(fp + 0);
        const float4 f1 = *(const float4*)(fp + 256);
        const float4 f2 = *(const float4*)(fp + 512);
        const float4 f3 = *(const float4*)(fp + 768);
        a0.x += w * f0.x;  a0.y += w * f0.y;  a0.z += w * f0.z;  a0.w += w * f0.w;
        a1.x += w * f1.x;  a1.y += w * f1.y;  a1.z += w * f1.z;  a1.w += w * f1.w;
        a2.x += w * f2.x;  a2.y += w * f2.y;  a2.z += w * f2.z;  a2.w += w * f2.w;
        a3.x += w * f3.x;  a3.y += w * f3.y;  a3.z += w * f3.z;  a3.w += w * f3.w;
    }

    float* op = out + (size_t)t * D + doff;
    *(float4*)(op + 0)   = a0;
    *(float4*)(op + 256) = a1;
    *(float4*)(op + 512) = a2;
    *(float4*)(op + 768) = a3;
}

extern "C" void kernel_launch(void* const* d_in, const int* in_sizes, int n_in,
                              void* d_out, int out_size, void* d_ws, size_t ws_size,
                              hipStream_t stream) {
    const float* h = (const float*)d_in[0];
    float* out = (float*)d_out;
    const int ntok = in_sizes[0] / D;               // 8192
    const int blocks = (ntok + 3) / 4;              // 2048 blocks, 1 wave = 1 token
    future_encoder_kernel<<<blocks, 256, 0, stream>>>(h, out, ntok);
}

// Round 6
// 115.746 us; speedup vs baseline: 1.6024x; 1.6024x over previous
//
#include <hip/hip_runtime.h>
#include <math.h>

// FutureEncoder: B=4, S=2048, D=1024, FUTURE_K=32, fp32 in/out.
// R6: R2 skeleton (online softmax, 2 tokens/wave, zero barriers, XCD swizzle)
// with: DPP wave-reduction (no ds_swizzle latency chain), branchy single-FMA
// online update (wave-uniform scores), explicit 2-row register double-buffer
// (all names, no runtime-indexed arrays -> no scratch).

constexpr int S = 2048;
constexpr int D = 1024;
constexpr int KF = 32;

template<int CTRL>
__device__ inline float dpp_add(float x) {
    int t = __builtin_amdgcn_update_dpp(0, __builtin_bit_cast(int, x),
                                        CTRL, 0xf, 0xf, true);
    return x + __builtin_bit_cast(float, t);
}

// full 64-lane sum, result broadcast to all lanes (via lane-63 readlane)
__device__ inline float wave_sum_u(float x) {
    x = dpp_add<0x111>(x);   // row_shr:1
    x = dpp_add<0x112>(x);   // row_shr:2
    x = dpp_add<0x114>(x);   // row_shr:4
    x = dpp_add<0x118>(x);   // row_shr:8
    x = dpp_add<0x142>(x);   // row_bcast:15
    x = dpp_add<0x143>(x);   // row_bcast:31
    int s = __builtin_amdgcn_readlane(__builtin_bit_cast(int, x), 63);
    return __builtin_bit_cast(float, s);
}

struct Row { float4 c0, c1, c2, c3; };

__device__ inline void loadRow(const float* p, Row& r) {
    r.c0 = *(const float4*)(p);
    r.c1 = *(const float4*)(p + 256);
    r.c2 = *(const float4*)(p + 512);
    r.c3 = *(const float4*)(p + 768);
}

__device__ inline float dotRow(const Row& q, const Row& f) {
    float d0 = q.c0.x*f.c0.x + q.c0.y*f.c0.y + q.c0.z*f.c0.z + q.c0.w*f.c0.w;
    float d1 = q.c1.x*f.c1.x + q.c1.y*f.c1.y + q.c1.z*f.c1.z + q.c1.w*f.c1.w;
    float d2 = q.c2.x*f.c2.x + q.c2.y*f.c2.y + q.c2.z*f.c2.z + q.c2.w*f.c2.w;
    float d3 = q.c3.x*f.c3.x + q.c3.y*f.c3.y + q.c3.z*f.c3.z + q.c3.w*f.c3.w;
    return (d0 + d1) + (d2 + d3);
}

#define FMA4(dst, A, B, C) \
    dst.x = fmaf(A, B.x, C.x); dst.y = fmaf(A, B.y, C.y); \
    dst.z = fmaf(A, B.z, C.z); dst.w = fmaf(A, B.w, C.w);

// online-softmax step; p is wave-uniform (post-readlane), valid is wave-uniform.
// Both paths: ONE fma per accumulated element.
__device__ inline void step(bool valid, float p, const Row& f,
                            Row& a, float& m, float& l) {
    if (!valid) return;
    if (p <= m) {
        float e = __expf(p - m);
        l += e;
        FMA4(a.c0, e, f.c0, a.c0); FMA4(a.c1, e, f.c1, a.c1);
        FMA4(a.c2, e, f.c2, a.c2); FMA4(a.c3, e, f.c3, a.c3);
    } else {
        float r = __expf(m - p);   // first step: exp(-huge)=0 -> a=f, l=1
        m = p;
        l = fmaf(l, r, 1.0f);
        FMA4(a.c0, r, a.c0, f.c0); FMA4(a.c1, r, a.c1, f.c1);
        FMA4(a.c2, r, a.c2, f.c2); FMA4(a.c3, r, a.c3, f.c3);
    }
}

__global__ __launch_bounds__(256, 3)
void future_encoder_kernel(const float* __restrict__ h,
                           float* __restrict__ out,
                           int ntok) {
    // XCD swizzle: contiguous block chunk per XCD (~4 MiB working set = its L2)
    int bid = blockIdx.x, nblk = gridDim.x, lb = bid;
    if ((nblk & 7) == 0) { int per = nblk >> 3; lb = (bid & 7) * per + (bid >> 3); }

    const int pid = lb * 4 + (threadIdx.x >> 6);   // pair id
    const int t0  = pid * 2;                       // tokens t0, t0+1 (t0 even)
    if (t0 >= ntok) return;
    const int lane  = threadIdx.x & 63;
    const int s0    = t0 & (S - 1);
    const int kmax0 = min(KF, (S - 1) - s0);       // >= 1
    const int kmax1 = min(KF, (S - 2) - s0);       // >= 0
    const int  tmax = ntok - 1;
    const int  doff = lane * 4;

    const float* base = h + (size_t)t0 * D + doff;
    Row q0, q1;
    loadRow(base, q0);
    loadRow(base + D, q1);

    Row a0 = {}, a1 = {};
    float m0 = -1e30f, l0 = 0.f, m1 = -1e30f, l1 = 0.f;

    // j=0: row t0+1 == q1 (no load); token0 only
    {
        float p = wave_sum_u(dotRow(q0, q1));
        step(true, p, q1, a0, m0, l0);
    }

    // preload rows j=1,2  (global rows t0+2, t0+3)
    Row fA, fB;
    {
        int r1 = min(t0 + 2, tmax), r2 = min(t0 + 3, tmax);
        loadRow(h + (size_t)r1 * D + doff, fA);
        loadRow(h + (size_t)r2 * D + doff, fB);
    }

    #pragma unroll 4
    for (int g = 0; g < 16; ++g) {
        const int j1 = 2 * g + 1, j2 = 2 * g + 2;

        Row nA, nB;                       // prefetch next group's rows
        if (g < 15) {
            int r1 = min(t0 + 2 * g + 4, tmax);
            int r2 = min(t0 + 2 * g + 5, tmax);
            loadRow(h + (size_t)r1 * D + doff, nA);
            loadRow(h + (size_t)r2 * D + doff, nB);
        }

        // 4 independent dot chains, then 4 independent DPP reductions
        float pA0 = dotRow(q0, fA);
        float pB0 = dotRow(q0, fB);
        float pA1 = dotRow(q1, fA);
        float pB1 = dotRow(q1, fB);
        pA0 = wave_sum_u(pA0);
        pB0 = wave_sum_u(pB0);
        pA1 = wave_sum_u(pA1);
        pB1 = wave_sum_u(pB1);

        step(j1 <  kmax0, pA0, fA, a0, m0, l0);
        step(j2 <  kmax0, pB0, fB, a0, m0, l0);
        step(j1 <= kmax1, pA1, fA, a1, m1, l1);
        step(j2 <= kmax1, pB1, fB, a1, m1, l1);

        if (g < 15) { fA = nA; fB = nB; }
    }

    const float inv0 = 1.0f / l0;                       // token0 always valid
    const float inv1 = (kmax1 > 0) ? (1.0f / l1) : 0.f; // s0==2046 -> zeros

    float* o = out + (size_t)t0 * D + doff;
    float4 r;
    r = a0.c0; r.x*=inv0; r.y*=inv0; r.z*=inv0; r.w*=inv0; *(float4*)(o +   0) = r;
    r = a0.c1; r.x*=inv0; r.y*=inv0; r.z*=inv0; r.w*=inv0; *(float4*)(o + 256) = r;
    r = a0.c2; r.x*=inv0; r.y*=inv0; r.z*=inv0; r.w*=inv0; *(float4*)(o + 512) = r;
    r = a0.c3; r.x*=inv0; r.y*=inv0; r.z*=inv0; r.w*=inv0; *(float4*)(o + 768) = r;
    float* o1 = o + D;
    r = a1.c0; r.x*=inv1; r.y*=inv1; r.z*=inv1; r.w*=inv1; *(float4*)(o1 +   0) = r;
    r = a1.c1; r.x*=inv1; r.y*=inv1; r.z*=inv1; r.w*=inv1; *(float4*)(o1 + 256) = r;
    r = a1.c2; r.x*=inv1; r.y*=inv1; r.z*=inv1; r.w*=inv1; *(float4*)(o1 + 512) = r;
    r = a1.c3; r.x*=inv1; r.y*=inv1; r.z*=inv1; r.w*=inv1; *(float4*)(o1 + 768) = r;
}

extern "C" void kernel_launch(void* const* d_in, const int* in_sizes, int n_in,
                              void* d_out, int out_size, void* d_ws, size_t ws_size,
                              hipStream_t stream) {
    const float* h = (const float*)d_in[0];
    float* out = (float*)d_out;
    const int ntok  = in_sizes[0] / D;     // 8192
    const int pairs = (ntok + 1) / 2;      // 4096
    const int blocks = (pairs + 3) / 4;    // 1024 blocks, 4 pairs (waves) each
    future_encoder_kernel<<<blocks, 256, 0, stream>>>(h, out, ntok);
}

// Round 8
// 108.543 us; speedup vs baseline: 1.7088x; 1.0664x over previous
//
#include <hip/hip_runtime.h>
#include <math.h>

// FutureEncoder: B=4, S=2048, D=1024, FUTURE_K=32, fp32 in/out.
// R8 (= R7 with compile fix): MFMA scores with cheap split-fp16 conversion
// (v_cvt_pkrtz packed RTZ, hi+lo, lo*lo dropped), G=8 tokens/block (1024
// blocks, 4/CU), LDS reduce+softmax, phase-2 fp32 PV with depth-2
// named-register prefetch and fixed 40-row trip count. XCD swizzle.

constexpr int S = 2048;
constexpr int D = 1024;
constexpr int G = 8;
constexpr int SCP = G * 49;          // per-wave partial-score stride (pad 49)

typedef __fp16   fp16x2 __attribute__((ext_vector_type(2)));   // cvt_pkrtz return type
typedef _Float16 half8  __attribute__((ext_vector_type(8)));
typedef float    f32x4  __attribute__((ext_vector_type(4)));

// 8 fp32 -> fp16 hi (RTZ, packed cvt) + fp16 lo (residual). ~24 VALU.
__device__ inline void cvt8(const float* p, half8& hi, half8& lo) {
    float4 x0 = *(const float4*)p;
    float4 x1 = *(const float4*)(p + 4);
    fp16x2 h0 = __builtin_amdgcn_cvt_pkrtz(x0.x, x0.y);
    fp16x2 h1 = __builtin_amdgcn_cvt_pkrtz(x0.z, x0.w);
    fp16x2 h2 = __builtin_amdgcn_cvt_pkrtz(x1.x, x1.y);
    fp16x2 h3 = __builtin_amdgcn_cvt_pkrtz(x1.z, x1.w);
    fp16x2 l0 = __builtin_amdgcn_cvt_pkrtz(x0.x - (float)h0[0], x0.y - (float)h0[1]);
    fp16x2 l1 = __builtin_amdgcn_cvt_pkrtz(x0.z - (float)h1[0], x0.w - (float)h1[1]);
    fp16x2 l2 = __builtin_amdgcn_cvt_pkrtz(x1.x - (float)h2[0], x1.y - (float)h2[1]);
    fp16x2 l3 = __builtin_amdgcn_cvt_pkrtz(x1.z - (float)h3[0], x1.w - (float)h3[1]);
    hi[0]=(_Float16)h0[0]; hi[1]=(_Float16)h0[1]; hi[2]=(_Float16)h1[0]; hi[3]=(_Float16)h1[1];
    hi[4]=(_Float16)h2[0]; hi[5]=(_Float16)h2[1]; hi[6]=(_Float16)h3[0]; hi[7]=(_Float16)h3[1];
    lo[0]=(_Float16)l0[0]; lo[1]=(_Float16)l0[1]; lo[2]=(_Float16)l1[0]; lo[3]=(_Float16)l1[1];
    lo[4]=(_Float16)l2[0]; lo[5]=(_Float16)l2[1]; lo[6]=(_Float16)l3[0]; lo[7]=(_Float16)l3[1];
}

#define MFMA3(ACC, AH, AL, BH, BL) \
    ACC = __builtin_amdgcn_mfma_f32_16x16x32_f16(AH, BH, ACC, 0, 0, 0); \
    ACC = __builtin_amdgcn_mfma_f32_16x16x32_f16(AH, BL, ACC, 0, 0, 0); \
    ACC = __builtin_amdgcn_mfma_f32_16x16x32_f16(AL, BH, ACC, 0, 0, 0);

#define ACC8(FV, WA, WB) \
    A0.x += WA.x*FV.x; A0.y += WA.x*FV.y; A0.z += WA.x*FV.z; A0.w += WA.x*FV.w; \
    A1.x += WA.y*FV.x; A1.y += WA.y*FV.y; A1.z += WA.y*FV.z; A1.w += WA.y*FV.w; \
    A2.x += WA.z*FV.x; A2.y += WA.z*FV.y; A2.z += WA.z*FV.z; A2.w += WA.z*FV.w; \
    A3.x += WA.w*FV.x; A3.y += WA.w*FV.y; A3.z += WA.w*FV.z; A3.w += WA.w*FV.w; \
    A4.x += WB.x*FV.x; A4.y += WB.x*FV.y; A4.z += WB.x*FV.z; A4.w += WB.x*FV.w; \
    A5.x += WB.y*FV.x; A5.y += WB.y*FV.y; A5.z += WB.y*FV.z; A5.w += WB.y*FV.w; \
    A6.x += WB.z*FV.x; A6.y += WB.z*FV.y; A6.z += WB.z*FV.z; A6.w += WB.z*FV.w; \
    A7.x += WB.w*FV.x; A7.y += WB.w*FV.y; A7.z += WB.w*FV.z; A7.w += WB.w*FV.w;

__global__ __launch_bounds__(256, 4)
void future_encoder_kernel(const float* __restrict__ h,
                           float* __restrict__ out,
                           int ntok) {
    __shared__ float scp[4 * SCP];   // per-wave partial scores [w][m][j]
    __shared__ float wts[48 * G];    // normalized weights, transposed [j][i]

    // XCD swizzle: contiguous 128-block chunk per XCD (~4 MiB = its L2)
    int bid = blockIdx.x, nblk = gridDim.x, lb = bid;
    if ((nblk & 7) == 0) { int per = nblk >> 3; lb = (bid & 7) * per + (bid >> 3); }

    const int tid  = threadIdx.x;
    const int w    = tid >> 6;
    const int lane = tid & 63;
    const int t0   = lb * G;
    const int s0   = t0 & (S - 1);
    const int jlim = (S - 2) - s0;          // max in-sequence j
    const int tmax = ntok - 1;

    // ---------- Phase 1: banded scores via MFMA; wave w owns dims [w*256,+256)
    {
        const int m  = lane & 15;           // A row (token) / B row (band col)
        const int kq = (lane >> 4) << 3;    // k-chunk within K=32 step
        const int d0 = (w << 8) + kq;

        const float* ap = h + (size_t)(t0 + (m < G ? m : G - 1)) * D + d0;
        int r0 = t0 +  1 + m; if (r0 > tmax) r0 = tmax;
        int r1 = t0 + 17 + m; if (r1 > tmax) r1 = tmax;
        int r2 = t0 + 33 + m; if (r2 > tmax) r2 = tmax;
        const float* bp0 = h + (size_t)r0 * D + d0;
        const float* bp1 = h + (size_t)r1 * D + d0;
        const float* bp2 = h + (size_t)r2 * D + d0;

        f32x4 ac0 = {0,0,0,0}, ac1 = {0,0,0,0}, ac2 = {0,0,0,0};

        #pragma unroll 2
        for (int kk = 0; kk < 8; ++kk) {
            const int o = kk * 32;
            half8 ah, al, bh, bl;
            cvt8(ap + o, ah, al);
            cvt8(bp0 + o, bh, bl);  MFMA3(ac0, ah, al, bh, bl);
            cvt8(bp1 + o, bh, bl);  MFMA3(ac1, ah, al, bh, bl);
            cvt8(bp2 + o, bh, bl);  MFMA3(ac2, ah, al, bh, bl);
        }

        // C layout: col = lane&15 (j in tile), row = (lane>>4)*4 + reg (token)
        const int mr = (lane >> 4) * 4;
        #pragma unroll
        for (int r = 0; r < 4; ++r) {
            const int mm = mr + r;
            if (mm < G) {
                scp[w * SCP + mm * 49 +  0 + m] = ac0[r];
                scp[w * SCP + mm * 49 + 16 + m] = ac1[r];
                scp[w * SCP + mm * 49 + 32 + m] = ac2[r];
            }
        }
    }
    __syncthreads();

    // ---------- Phase 1.5: reduce 4 partials + softmax -> wts[j][i]
    {
        const int i   = tid >> 5;           // token 0..7
        const int sub = tid & 31;
        const int rb  = i * 49;

        float p0 = scp[0*SCP + rb + sub] + scp[1*SCP + rb + sub]
                 + scp[2*SCP + rb + sub] + scp[3*SCP + rb + sub];
        const bool va = (sub >= i) && (sub <= i + 31) && (sub <= jlim);
        float v0 = va ? p0 : -1e9f;

        const int j1 = 32 + sub;
        float v1 = -1e9f; bool vb = false;
        if (sub < 16) {
            float p1 = scp[0*SCP + rb + j1] + scp[1*SCP + rb + j1]
                     + scp[2*SCP + rb + j1] + scp[3*SCP + rb + j1];
            vb = (j1 <= i + 31) && (j1 <= jlim);
            v1 = vb ? p1 : -1e9f;
        }

        float mx = fmaxf(v0, v1);
        #pragma unroll
        for (int d = 1; d < 32; d <<= 1) mx = fmaxf(mx, __shfl_xor(mx, d, 32));

        float e0 = __expf(v0 - mx);
        float e1 = (sub < 16) ? __expf(v1 - mx) : 0.f;
        float sm = e0 + e1;
        #pragma unroll
        for (int d = 1; d < 32; d <<= 1) sm += __shfl_xor(sm, d, 32);

        const float inv = 1.0f / sm;        // all-invalid token masked below
        wts[sub * G + i] = va ? e0 * inv : 0.f;
        if (sub < 16) wts[j1 * G + i] = vb ? e1 * inv : 0.f;
    }
    __syncthreads();

    // ---------- Phase 2: PV fp32; wave w owns dims [w*256,+256), 4 dims/lane
    {
        const int dd = (w << 8) + (lane << 2);
        const float* hb = h + dd;

        // row pointer for band row j (clamped; invalid j has weight 0)
        #define ROWP(J) (hb + (size_t)((t0 + 1 + (J) > tmax) ? tmax : t0 + 1 + (J)) * D)

        float4 f0 = *(const float4*)ROWP(0);
        float4 f1 = *(const float4*)ROWP(1);
        float4 f2 = *(const float4*)ROWP(2);
        float4 f3 = *(const float4*)ROWP(3);

        float4 A0 = {}, A1 = {}, A2 = {}, A3 = {};
        float4 A4 = {}, A5 = {}, A6 = {}, A7 = {};

        for (int g = 0; g < 20; ++g) {              // rows j = 2g, 2g+1 (0..39)
            float4 n0, n1;
            if (g < 18) {
                n0 = *(const float4*)ROWP(2 * g + 4);
                n1 = *(const float4*)ROWP(2 * g + 5);
            }
            const int j = 2 * g;
            float4 wA = *(const float4*)&wts[j * G];
            float4 wB = *(const float4*)&wts[j * G + 4];
            float4 wC = *(const float4*)&wts[(j + 1) * G];
            float4 wD = *(const float4*)&wts[(j + 1) * G + 4];
            ACC8(f0, wA, wB);
            ACC8(f1, wC, wD);
            f0 = f2; f1 = f3; f2 = n0; f3 = n1;
        }
        #undef ROWP

        float* ob = out + (size_t)t0 * D + dd;
        *(float4*)(ob + 0 * D) = A0;
        *(float4*)(ob + 1 * D) = A1;
        *(float4*)(ob + 2 * D) = A2;
        *(float4*)(ob + 3 * D) = A3;
        *(float4*)(ob + 4 * D) = A4;
        *(float4*)(ob + 5 * D) = A5;
        *(float4*)(ob + 6 * D) = A6;
        *(float4*)(ob + 7 * D) = A7;
    }
}

extern "C" void kernel_launch(void* const* d_in, const int* in_sizes, int n_in,
                              void* d_out, int out_size, void* d_ws, size_t ws_size,
                              hipStream_t stream) {
    const float* h = (const float*)d_in[0];
    float* out = (float*)d_out;
    const int ntok = in_sizes[0] / D;        // 8192
    const int blocks = ntok / G;             // 1024
    future_encoder_kernel<<<blocks, 256, 0, stream>>>(h, out, ntok);
}